// Round 7
// baseline (81.768 us; speedup 1.0000x reference)
//
#include <hip/hip_runtime.h>

#define IN_F   1024
#define OUT_F  1024
#define KCOEF  97
#define RPW    256                  // rows per wave
#define RPC    8                    // rows per chunk
#define NCH    (RPW / RPC)          // 32 chunks
#define CFL    (RPC * KCOEF)        // 776 floats per chunk

typedef float f4 __attribute__((ext_vector_type(4)));

// once per call: x[b][i] (32x1024) -> xT[i][b] (1024x32), 128 KB, L2-resident
__global__ __launch_bounds__(256)
void transpose_x(const float* __restrict__ x, float* __restrict__ xT) {
    int t = blockIdx.x * 256 + threadIdx.x;    // t = b*IN_F + i (coalesced read)
    int b = t >> 10, i = t & 1023;
    xT[(i << 5) + b] = x[t];
}

// issue chunk c's loads to regs (w: 12 dwords + 8-lane tail; x: one f4)
#define ISSUE(c) do {                                                     \
    const float* _src = wslice + (c) * CFL;                               \
    _Pragma("unroll")                                                     \
    for (int _u = 0; _u < 12; ++_u) sw[_u] = _src[lane + (_u << 6)];      \
    if (lane < 8) swt = _src[768 + lane];                                 \
    sx = *(const f4*)&xslice[(c) * (RPC * 32) + (lane << 2)];             \
} while (0)

// write staged regs to this wave's LDS buffer cb_ (compiler emits vmcnt wait)
#define WRITE(cb_) do {                                                   \
    float* _dw = shw[wv][cb_];                                            \
    _Pragma("unroll")                                                     \
    for (int _u = 0; _u < 12; ++_u) _dw[lane + (_u << 6)] = sw[_u];       \
    if (lane < 8) _dw[768 + lane] = swt;                                  \
    *(f4*)&shx[wv][cb_][lane << 2] = sx;                                  \
} while (0)

// compute chunk in buffer cb_: half-wave h does rows 4h..4h+3
#define COMPUTE(cb_) do {                                                 \
    const float* _rows = shw[wv][cb_];                                    \
    const float* _xr   = shx[wv][cb_];                                    \
    _Pragma("unroll")                                                     \
    for (int _r4 = 0; _r4 < 4; ++_r4) {                                   \
        const int _r = (h << 2) + _r4;                                    \
        float _xv = _xr[(_r << 5) + bb];                                  \
        float _s = (_xv + 1.0f) * 16.0f;                                  \
        int _id = (int)_s;                                                \
        _id = _id < 0 ? 0 : (_id > 31 ? 31 : _id);                        \
        float _d  = _xv - ((float)_id * 0.0625f - 1.0f);                  \
        float _tt = fmaf(_d, 32.0f, -1.0f);                               \
        float _ap = _tt + 1.0f, _bp = _tt + 0.5f;                         \
        float _cm = _tt - 0.5f, _dm = _tt - 1.0f;                         \
        float _uu = _bp * _cm, _vv = _ap * _dm;                           \
        float _B0 = _uu * _dm * (-2.0f / 3.0f);                           \
        float _B1 = _vv * _cm * ( 4.0f / 3.0f);                           \
        float _B2 = _vv * _bp * (-4.0f / 3.0f);                           \
        float _B3 = _uu * _ap * ( 2.0f / 3.0f);                           \
        const float* _row = _rows + _r * KCOEF;                           \
        int _j3 = _id * 3;                                                \
        float _w0 = _row[_j3], _w1 = _row[_j3 + 1];                       \
        float _w2 = _row[_j3 + 2], _w3 = _row[_j3 + 3];                   \
        float _v = fmaf(_B0, _w0, fmaf(_B1, _w1,                          \
                   fmaf(_B2, _w2, _B3 * _w3)));                           \
        if (_r4 & 1) acc1 += _v; else acc0 += _v;                         \
    }                                                                     \
} while (0)

// Barrier-free main: each wave owns a private 256-row stream with its own
// double-buffered LDS region; only intra-wave waitcnt ordering is needed.
__global__ __launch_bounds__(256, 4)
void piecewise_main(const float* __restrict__ xT,
                    const float* __restrict__ w,
                    float* __restrict__ out) {
    const int bid = blockIdx.x;
    const int o = (bid & 7) * 128 + (bid >> 3);   // bijective XCD swizzle
    const int t    = threadIdx.x;
    const int wv   = t >> 6;        // wave 0..3
    const int lane = t & 63;
    const int h    = lane >> 5;     // half-wave
    const int bb   = lane & 31;     // batch lane

    __shared__ __align__(16) float shw[4][2][CFL];       // 24832 B
    __shared__ __align__(16) float shx[4][2][RPC * 32];  //  8192 B
    __shared__ float red[256];

    const float* wslice = w + (size_t)o * (IN_F * KCOEF) + wv * (RPW * KCOEF);
    const float* xslice = xT + wv * (RPW * 32);

    float sw[12], swt;
    f4 sx;
    float acc0 = 0.f, acc1 = 0.f;

    ISSUE(0);
    WRITE(0);

    for (int c = 0; c < NCH; ++c) {
        const int cb = c & 1;
        if (c + 1 < NCH) ISSUE(c + 1);     // next chunk's loads in flight
        COMPUTE(cb);
        if (c + 1 < NCH) WRITE(cb ^ 1);    // waits only this wave's loads
    }

    // block-level reduce: 8 partials (4 waves x 2 halves) per batch lane
    red[t] = acc0 + acc1;
    __syncthreads();
    if (t < 32) {
        float sum = red[t];
        #pragma unroll
        for (int gg = 1; gg < 8; ++gg) sum += red[gg * 32 + t];
        out[t * OUT_F + o] = sum;
    }
}

extern "C" void kernel_launch(void* const* d_in, const int* in_sizes, int n_in,
                              void* d_out, int out_size, void* d_ws, size_t ws_size,
                              hipStream_t stream) {
    const float* x = (const float*)d_in[0];
    const float* w = (const float*)d_in[1];
    float*       out = (float*)d_out;
    float*       xT  = (float*)d_ws;   // 128 KB

    transpose_x<<<(32 * IN_F) / 256, 256, 0, stream>>>(x, xT);
    piecewise_main<<<OUT_F, 256, 0, stream>>>(xT, w, out);
}

// Round 8
// 80.718 us; speedup vs baseline: 1.0130x; 1.0130x over previous
//
#include <hip/hip_runtime.h>

#define IN_F   1024
#define OUT_F  1024
#define KCOEF  97
#define CROWS  32                    // rows per chunk
#define CFL    (CROWS * KCOEF)       // 3104 floats
#define CB     (CFL * 4)             // 12416 bytes
#define NCH    32

typedef float f4 __attribute__((ext_vector_type(4)));

#define AS1 __attribute__((address_space(1)))
#define AS3 __attribute__((address_space(3)))

// pack x: xq[(i>>2)*128 + b*4 + (i&3)] = x[b*1024 + i]
// -> thread (g,b) of chunk c reads its 4 x-values as ONE aligned f4.
__global__ __launch_bounds__(256)
void pack_x(const float* __restrict__ x, float* __restrict__ xq) {
    int t = blockIdx.x * 256 + threadIdx.x;    // b*1024 + i (coalesced read)
    int b = t >> 10, i = t & 1023;
    xq[((i >> 2) << 7) + (b << 2) + (i & 3)] = x[t];
}

// chunk c -> LDS buffer buf_ via DMA. Exactly 4 instrs per wave (uniform vmcnt):
// 3 full (64 lanes x 16B) + 1 tail (2 lanes x 16B per wave).
#define ISSUE_W(c, buf_) do {                                                   \
    const char* _gw = wbase + (size_t)(c) * CB;                                 \
    char* _lw = (char*)&shw[buf_][0];                                           \
    _Pragma("unroll")                                                           \
    for (int _k = 0; _k < 3; ++_k)                                              \
        __builtin_amdgcn_global_load_lds(                                       \
            (const AS1 void*)(_gw + (_k << 12) + (t << 4)),                     \
            (AS3 void*)(_lw + (_k << 12) + (wv << 10)), 16, 0, 0);              \
    if (lane < 2)                                                               \
        __builtin_amdgcn_global_load_lds(                                       \
            (const AS1 void*)(_gw + 12288 + (wv << 5) + (lane << 4)),           \
            (AS3 void*)(_lw + 12288 + (wv << 5)), 16, 0, 0);                    \
} while (0)

// x quad for chunk c, rows 4g..4g+3: one f4
#define XLOAD(c) (*(const f4*)&xq[((((c) << 3) + g) << 7) + (b << 2)])

// register-only basis+index from an x-quad (A/B sets, constant-indexed)
#define BASIS(b_, j_, xv_) do {                                           \
    _Pragma("unroll")                                                     \
    for (int _r = 0; _r < 4; ++_r) {                                      \
        float _x = xv_[_r];                                               \
        float _s = (_x + 1.0f) * 16.0f;                                   \
        int _id = (int)_s;                                                \
        _id = _id < 0 ? 0 : (_id > 31 ? 31 : _id);                        \
        float _d  = _x - ((float)_id * 0.0625f - 1.0f);                   \
        float _tt = fmaf(_d, 32.0f, -1.0f);                               \
        float _ap = _tt + 1.0f, _bp = _tt + 0.5f;                         \
        float _cm = _tt - 0.5f, _dm = _tt - 1.0f;                         \
        float _uu = _bp * _cm, _vv = _ap * _dm;                           \
        b_[_r][0] = _uu * _dm * (-2.0f / 3.0f);                           \
        b_[_r][1] = _vv * _cm * ( 4.0f / 3.0f);                           \
        b_[_r][2] = _vv * _bp * (-4.0f / 3.0f);                           \
        b_[_r][3] = _uu * _ap * ( 2.0f / 3.0f);                           \
        j_[_r] = _id * 3;                                                 \
    }                                                                     \
} while (0)

// LDS gather + fma for the chunk in buf_ (VMEM-free)
#define COMPUTE(b_, j_, buf_) do {                                        \
    const float* _rows = &shw[buf_][(g << 2) * KCOEF];                    \
    _Pragma("unroll")                                                     \
    for (int _r = 0; _r < 4; ++_r) {                                      \
        const float* _row = _rows + _r * KCOEF;                           \
        int _j = j_[_r];                                                  \
        float _w0 = _row[_j], _w1 = _row[_j + 1];                         \
        float _w2 = _row[_j + 2], _w3 = _row[_j + 3];                     \
        float _v = fmaf(b_[_r][0], _w0, fmaf(b_[_r][1], _w1,              \
                   fmaf(b_[_r][2], _w2, b_[_r][3] * _w3)));               \
        if (_r & 1) acc1 += _v; else acc0 += _v;                          \
    }                                                                     \
} while (0)

#define SBAR0() __builtin_amdgcn_sched_barrier(0)

// counted-vmcnt barrier: waits prior chunk's 4 DMAs + the x load, leaves the
// just-issued 4 in flight. Never drains to 0 in the main loop.
#define WAITBAR(N) do {                                                   \
    asm volatile("s_waitcnt vmcnt(" #N ")" ::: "memory");                 \
    SBAR0();                                                              \
    __builtin_amdgcn_s_barrier();                                         \
    SBAR0();                                                              \
} while (0)

#define ENDBAR() do {                                                     \
    SBAR0();                                                              \
    __builtin_amdgcn_s_barrier();                                         \
    SBAR0();                                                              \
} while (0)

__global__ __launch_bounds__(256, 4)
void piecewise_main(const float* __restrict__ xq,
                    const float* __restrict__ w,
                    float* __restrict__ out) {
    const int bid = blockIdx.x;
    const int o = (bid & 7) * 128 + (bid >> 3);   // bijective XCD swizzle
    const int t    = threadIdx.x;
    const int wv   = t >> 6;
    const int lane = t & 63;
    const int g    = t >> 5;      // row-group 0..7
    const int b    = t & 31;      // batch lane

    __shared__ __align__(16) float shw[3][CFL];   // 37248 B
    __shared__ float red[256];

    const char* wbase = (const char*)(w + (size_t)o * (IN_F * KCOEF));

    float bA[4][4], bB[4][4];
    int   jA[4],   jB[4];
    float acc0 = 0.f, acc1 = 0.f;

    // prologue: x0 -> basisA; chunks 0,1 DMA in flight
    f4 xv0 = XLOAD(0);
    SBAR0();
    ISSUE_W(0, 0);
    ISSUE_W(1, 1);
    BASIS(bA, jA, xv0);           // compiler waits only the x load

    for (int cc = 0; cc < 30; cc += 2) {
        const int p0 = cc % 3, p1 = (cc + 1) % 3, p2 = (cc + 2) % 3;
        // half 1: compute cc (A), prep cc+1 (B), issue cc+2
        f4 xv1 = XLOAD(cc + 1);
        SBAR0();                  // pin x load before the DMAs
        ISSUE_W(cc + 2, p2);
        WAITBAR(4);               // waits chunk cc+1 DMA + x; leaves cc+2
        BASIS(bB, jB, xv1);
        COMPUTE(bA, jA, p0);
        ENDBAR();                 // protects buf p0 before cc+3 overwrites it
        // half 2: compute cc+1 (B), prep cc+2 (A), issue cc+3
        f4 xv2 = XLOAD(cc + 2);
        SBAR0();
        ISSUE_W(cc + 3, p0);
        WAITBAR(4);               // waits chunk cc+2 DMA + x; leaves cc+3
        BASIS(bA, jA, xv2);
        COMPUTE(bB, jB, p1);
        ENDBAR();                 // protects buf p1 before cc+4 overwrites it
    }

    // epilogue: chunks 30 (basisA ready, buf0 ready) and 31 (buf1, DMA in flight)
    f4 xv31 = XLOAD(31);
    asm volatile("s_waitcnt vmcnt(0)" ::: "memory");   // end of stream: drain
    SBAR0();
    __builtin_amdgcn_s_barrier();
    SBAR0();
    BASIS(bB, jB, xv31);
    COMPUTE(bA, jA, 0);
    COMPUTE(bB, jB, 1);

    // reduce 8 group-partials per (b, o)
    red[t] = acc0 + acc1;
    __syncthreads();
    if (t < 32) {
        float sum = red[t];
        #pragma unroll
        for (int gg = 1; gg < 8; ++gg) sum += red[gg * 32 + t];
        out[t * OUT_F + o] = sum;
    }
}

extern "C" void kernel_launch(void* const* d_in, const int* in_sizes, int n_in,
                              void* d_out, int out_size, void* d_ws, size_t ws_size,
                              hipStream_t stream) {
    const float* x = (const float*)d_in[0];
    const float* w = (const float*)d_in[1];
    float*       out = (float*)d_out;
    float*       xq  = (float*)d_ws;   // 128 KB, L2-resident

    pack_x<<<(32 * IN_F) / 256, 256, 0, stream>>>(x, xq);
    piecewise_main<<<OUT_F, 256, 0, stream>>>(xq, w, out);
}

// Round 9
// 75.665 us; speedup vs baseline: 1.0807x; 1.0668x over previous
//
#include <hip/hip_runtime.h>

#define IN_F   1024
#define OUT_F  1024
#define KCOEF  97
#define CROWS  32                    // rows per chunk
#define CFL    (CROWS * KCOEF)       // 3104 floats
#define CB     (CFL * 4)             // 12416 bytes

typedef float f4 __attribute__((ext_vector_type(4)));

#define AS1 __attribute__((address_space(1)))
#define AS3 __attribute__((address_space(3)))

#define SBAR0() __builtin_amdgcn_sched_barrier(0)

// chunk c -> LDS buffer (char* lbuf) via DMA: 3 full instrs + 1 two-lane tail
// = exactly 5 vmcnt entries per wave, uniform across waves.
#define ISSUE_W(c, lbuf) do {                                                   \
    const char* _g = wbase + (size_t)(c) * CB;                                  \
    _Pragma("unroll")                                                           \
    for (int _k = 0; _k < 3; ++_k)                                              \
        __builtin_amdgcn_global_load_lds(                                       \
            (const AS1 void*)(_g + (_k << 12) + (t << 4)),                      \
            (AS3 void*)((lbuf) + (_k << 12) + (wv << 10)), 16, 0, 0);           \
    if (lane < 2)                                                               \
        __builtin_amdgcn_global_load_lds(                                       \
            (const AS1 void*)(_g + 12288 + (wv << 5) + (lane << 4)),            \
            (AS3 void*)((lbuf) + 12288 + (wv << 5)), 16, 0, 0);                 \
} while (0)

// x quad for chunk c, rows 4g..4g+3 of batch lane b: one aligned f4 (1 vmcnt)
#define XLOAD(c) (*(const f4*)&xrow[((c) << 5) + (g << 2)])

// register-only basis+index from an x-quad
#define BASIS(b_, j_, xv_) do {                                           \
    _Pragma("unroll")                                                     \
    for (int _r = 0; _r < 4; ++_r) {                                      \
        float _x = xv_[_r];                                               \
        float _s = (_x + 1.0f) * 16.0f;                                   \
        int _id = (int)_s;                                                \
        _id = _id < 0 ? 0 : (_id > 31 ? 31 : _id);                        \
        float _d  = _x - ((float)_id * 0.0625f - 1.0f);                   \
        float _tt = fmaf(_d, 32.0f, -1.0f);                               \
        float _ap = _tt + 1.0f, _bp = _tt + 0.5f;                         \
        float _cm = _tt - 0.5f, _dm = _tt - 1.0f;                         \
        float _uu = _bp * _cm, _vv = _ap * _dm;                           \
        b_[_r][0] = _uu * _dm * (-2.0f / 3.0f);                           \
        b_[_r][1] = _vv * _cm * ( 4.0f / 3.0f);                           \
        b_[_r][2] = _vv * _bp * (-4.0f / 3.0f);                           \
        b_[_r][3] = _uu * _ap * ( 2.0f / 3.0f);                           \
        j_[_r] = _id * 3;                                                 \
    }                                                                     \
} while (0)

// LDS gather + fma for the chunk in buffer q_ (pure LDS, no VMEM)
#define COMPUTE(b_, j_, q_) do {                                          \
    const float* _rows = (const float*)(q_) + (g << 2) * KCOEF;           \
    _Pragma("unroll")                                                     \
    for (int _r = 0; _r < 4; ++_r) {                                      \
        const float* _row = _rows + _r * KCOEF;                           \
        int _j = j_[_r];                                                  \
        float _w0 = _row[_j], _w1 = _row[_j + 1];                         \
        float _w2 = _row[_j + 2], _w3 = _row[_j + 3];                     \
        float _v = fmaf(b_[_r][0], _w0, fmaf(b_[_r][1], _w1,              \
                   fmaf(b_[_r][2], _w2, b_[_r][3] * _w3)));               \
        if (_r & 1) acc1 += _v; else acc0 += _v;                          \
    }                                                                     \
} while (0)

// counted wait: drain oldest chunk only (6 = x(c+1) + W(c+1)'s 5 stay in
// flight), then barrier = buffer-protect + collective data-ready.
#define WAITBAR(N) do {                                                   \
    asm volatile("s_waitcnt vmcnt(" #N ")" ::: "memory");                 \
    SBAR0();                                                              \
    __builtin_amdgcn_s_barrier();                                         \
    SBAR0();                                                              \
} while (0)

__global__ __launch_bounds__(256, 4)
void piecewise_fused(const float* __restrict__ x,
                     const float* __restrict__ w,
                     float* __restrict__ out) {
    const int bid = blockIdx.x;
    const int o = (bid & 7) * 128 + (bid >> 3);   // bijective XCD swizzle
    const int t    = threadIdx.x;
    const int wv   = t >> 6;
    const int lane = t & 63;
    const int g    = t >> 5;      // row-group 0..7
    const int b    = t & 31;      // batch lane

    __shared__ __align__(16) float shw[3][CFL];   // 37248 B
    __shared__ float red[256];

    const char*  wbase = (const char*)(w + (size_t)o * (IN_F * KCOEF));
    const float* xrow  = x + b * IN_F;

    char* q0 = (char*)&shw[0][0];   // chunk c
    char* q1 = (char*)&shw[1][0];   // chunk c+1
    char* q2 = (char*)&shw[2][0];   // free (target for c+2)

    float bA[4][4], bB[4][4];
    int   jA[4],   jB[4];
    f4 xvA, xvB;
    float acc0 = 0.f, acc1 = 0.f;

    // prologue: basis(0) from x(0); chunks 0,1 DMA in flight; x(1) in flight
    xvA = XLOAD(0);
    BASIS(bA, jA, xvA);           // compiler drains only x(0)
    ISSUE_W(0, q0);
    xvB = XLOAD(1);
    ISSUE_W(1, q1);

    for (int cc = 0; cc < 30; cc += 2) {
        // half 1: compute cc.  Outstanding: W(cc)5, x(cc+1), W(cc+1)5 = 11
        WAITBAR(6);               // drain W(cc); leave x(cc+1)+W(cc+1)
        xvA = XLOAD(cc + 2);
        ISSUE_W(cc + 2, q2);      // depth 2: W(cc+1)+W(cc+2) in flight
        COMPUTE(bA, jA, q0);
        SBAR0();
        BASIS(bB, jB, xvB);       // basis(cc+1); waits only x(cc+1)
        // half 2: compute cc+1.  Outstanding: W(cc+1)5, x(cc+2), W(cc+2)5
        WAITBAR(6);               // drain W(cc+1)
        xvB = XLOAD(cc + 3);
        ISSUE_W(cc + 3, q0);      // into chunk cc's buffer (barrier-protected)
        COMPUTE(bB, jB, q1);
        SBAR0();
        BASIS(bA, jA, xvA);       // basis(cc+2)
        char* tmp = q0; q0 = q2; q2 = q1; q1 = tmp;
    }

    // epilogue: chunks 30 (q0) and 31 (q1). Outstanding: W(30)5, x(31), W(31)5
    WAITBAR(6);                   // drain W(30)
    COMPUTE(bA, jA, q0);
    SBAR0();
    BASIS(bB, jB, xvB);           // basis(31); waits x(31)
    WAITBAR(0);                   // drain W(31)
    COMPUTE(bB, jB, q1);

    // reduce 8 group-partials per (b, o)
    red[t] = acc0 + acc1;
    __syncthreads();
    if (t < 32) {
        float sum = red[t];
        #pragma unroll
        for (int gg = 1; gg < 8; ++gg) sum += red[gg * 32 + t];
        out[t * OUT_F + o] = sum;
    }
}

extern "C" void kernel_launch(void* const* d_in, const int* in_sizes, int n_in,
                              void* d_out, int out_size, void* d_ws, size_t ws_size,
                              hipStream_t stream) {
    const float* x = (const float*)d_in[0];
    const float* w = (const float*)d_in[1];
    float*       out = (float*)d_out;
    piecewise_fused<<<OUT_F, 256, 0, stream>>>(x, w, out);
}

// Round 10
// 74.214 us; speedup vs baseline: 1.1018x; 1.0196x over previous
//
#include <hip/hip_runtime.h>

#define IN_F   1024
#define OUT_F  1024
#define KCOEF  97
#define CROWS  32                       // rows per chunk
#define CFLOATS (CROWS * KCOEF)         // 3104 floats
#define CBYTES  (CFLOATS * 4)           // 12416 B
#define NCHUNK (IN_F / CROWS)           // 32
#define XSTRIDE 33                      // padded x-transpose stride

typedef float f4 __attribute__((ext_vector_type(4)));

// w-chunk -> LDS via direct DMA (global_load_lds, 16B/lane). Linear dest:
// 3 full-block instrs (4096B each) + one 8-lane tail (128B).
#define ISSUE_W(c, cb_) do {                                                    \
    const char* _base = wslice + (size_t)(c) * CBYTES;                          \
    char* _lbase = (char*)&shw[cb_][0];                                         \
    _Pragma("unroll")                                                           \
    for (int _k = 0; _k < 3; ++_k)                                              \
        __builtin_amdgcn_global_load_lds(                                       \
            (const __attribute__((address_space(1))) void*)(_base + (_k << 12) + (t << 4)), \
            (__attribute__((address_space(3))) void*)(_lbase + (_k << 12) + ((t >> 6) << 10)), \
            16, 0, 0);                                                          \
    if (t < 8)                                                                  \
        __builtin_amdgcn_global_load_lds(                                       \
            (const __attribute__((address_space(1))) void*)(_base + 12288 + (t << 4)), \
            (__attribute__((address_space(3))) void*)(_lbase + 12288),          \
            16, 0, 0);                                                          \
} while (0)

// x-slice: one f4 load per thread (32 b x 32 i per chunk)
#define ISSUE_X(c) do {                                                   \
    sx = *(const f4*)&x[(t >> 3) * IN_F + (c) * CROWS + ((t & 7) << 2)];  \
} while (0)

// transposed x write: [i_local][b], stride 33 -> conflict-free reads
#define WRITE_X(cb_) do {                                                 \
    float* _dx = xsh[cb_];                                                \
    const int _bs = t >> 3, _j4 = (t & 7) << 2;                           \
    _dx[(_j4    ) * XSTRIDE + _bs] = sx.x;                                \
    _dx[(_j4 + 1) * XSTRIDE + _bs] = sx.y;                                \
    _dx[(_j4 + 2) * XSTRIDE + _bs] = sx.z;                                \
    _dx[(_j4 + 3) * XSTRIDE + _bs] = sx.w;                                \
} while (0)

// inline basis + 4-coeff LDS gather for chunk in buffer cb_
#define COMPUTE(cb_) do {                                                 \
    const float* _rows = &shw[cb_][(g << 2) * KCOEF];                     \
    _Pragma("unroll")                                                     \
    for (int _r = 0; _r < 4; ++_r) {                                      \
        float _xv = xsh[cb_][((g << 2) + _r) * XSTRIDE + b];              \
        float _s = (_xv + 1.0f) * 16.0f;                                  \
        int _id = (int)_s;                                                \
        _id = _id < 0 ? 0 : (_id > 31 ? 31 : _id);                        \
        float _d  = _xv - ((float)_id * 0.0625f - 1.0f);                  \
        float _tt = fmaf(_d, 32.0f, -1.0f);                               \
        float _ap = _tt + 1.0f, _bp = _tt + 0.5f;                         \
        float _cm = _tt - 0.5f, _dm = _tt - 1.0f;                         \
        float _uu = _bp * _cm, _vv = _ap * _dm;                           \
        float _B0 = _uu * _dm * (-2.0f / 3.0f);                           \
        float _B1 = _vv * _cm * ( 4.0f / 3.0f);                           \
        float _B2 = _vv * _bp * (-4.0f / 3.0f);                           \
        float _B3 = _uu * _ap * ( 2.0f / 3.0f);                           \
        const float* _row = _rows + _r * KCOEF;                           \
        int _j3 = _id * 3;                                                \
        float _w0 = _row[_j3], _w1 = _row[_j3 + 1];                       \
        float _w2 = _row[_j3 + 2], _w3 = _row[_j3 + 3];                   \
        float _v = fmaf(_B0, _w0, fmaf(_B1, _w1,                          \
                   fmaf(_B2, _w2, _B3 * _w3)));                           \
        if (_r & 1) acc1 += _v; else acc0 += _v;                          \
    }                                                                     \
} while (0)

__global__ __launch_bounds__(256, 4)
void piecewise_fused(const float* __restrict__ x,
                     const float* __restrict__ w,
                     float* __restrict__ out) {
    // bijective XCD swizzle: 1024 % 8 == 0
    const int bid = blockIdx.x;
    const int o = (bid & 7) * 128 + (bid >> 3);
    const int t = threadIdx.x;
    const int b = t & 31;     // batch lane
    const int g = t >> 5;     // row-group 0..7 (4 rows each)

    __shared__ __align__(16) float shw[2][CFLOATS];
    __shared__ float xsh[2][CROWS * XSTRIDE];
    __shared__ float red[256];

    const char* wslice = (const char*)(w + (size_t)o * (IN_F * KCOEF));

    f4 sx;
    float acc0 = 0.f, acc1 = 0.f;

    // prologue: chunk 0 DMA + x stage
    ISSUE_W(0, 0);
    ISSUE_X(0);
    WRITE_X(0);
    __syncthreads();                       // drains DMA + LDS writes

    for (int c = 0; c < NCHUNK; ++c) {
        const int cb = c & 1;
        if (c + 1 < NCHUNK) {
            ISSUE_W(c + 1, cb ^ 1);        // DMA next chunk, in flight over compute
            ISSUE_X(c + 1);
        }
        COMPUTE(cb);
        if (c + 1 < NCHUNK) WRITE_X(cb ^ 1);
        __syncthreads();
    }

    // reduce 8 group-partials per (b, o)
    red[t] = acc0 + acc1;
    __syncthreads();
    if (t < 32) {
        float sum = red[t];
        #pragma unroll
        for (int gg = 1; gg < 8; ++gg) sum += red[gg * 32 + t];
        out[t * OUT_F + o] = sum;
    }
}

extern "C" void kernel_launch(void* const* d_in, const int* in_sizes, int n_in,
                              void* d_out, int out_size, void* d_ws, size_t ws_size,
                              hipStream_t stream) {
    const float* x = (const float*)d_in[0];
    const float* w = (const float*)d_in[1];
    float*       out = (float*)d_out;
    piecewise_fused<<<OUT_F, 256, 0, stream>>>(x, w, out);
}